// Round 4
// baseline (1225.032 us; speedup 1.0000x reference)
//
#include <hip/hip_runtime.h>
#include <hip/hip_bf16.h>

#define N_NODES 50000
#define DEG     16
#define IN_CH   128
#define TYPE_DIM 32
#define F_DIM   160      // = IN_CH + TYPE_DIM
#define H_DIM   160
#define OUT_CH  128
#define NSTEP   16       // = DEG timesteps
#define LS      168      // LDS row stride in ushorts (16B-aligned, +8 pad)
#define BROWS   32       // nodes per block
#define NTHR    320      // 5 waves

typedef short  bf16x8 __attribute__((ext_vector_type(8)));
typedef float  f32x4  __attribute__((ext_vector_type(4)));
typedef unsigned int u32x4 __attribute__((ext_vector_type(4)));

// Workspace in __device__ globals (cached VRAM) — d_ws is mapped
// uncached/streaming. Fully rewritten every call.
__device__ ushort g_hin[N_NODES * F_DIM];       // 16,000,000 B
__device__ ushort g_wfrag[400 * 64 * 8];        // 409,600 B
__device__ ushort g_wlrfrag[80 * 64 * 8];       // 81,920 B
__device__ float  g_bsum[4 * H_DIM];            // 2,560 B

static __device__ __forceinline__ ushort f2bf(float v) {
    union { float f; unsigned u; } x; x.f = v;
    unsigned r = x.u + 0x7fff + ((x.u >> 16) & 1);   // RNE
    return (ushort)(r >> 16);
}
// v_rcp_f32 (1 instr) instead of IEEE division (~9 instr): R1 proved real win.
static __device__ __forceinline__ float sigmoid_fast(float x) {
    return __builtin_amdgcn_rcpf(1.f + __expf(-x));
}
static __device__ __forceinline__ float tanh_fast(float x) {
    float e = __expf(2.f * x);
    return 1.f - 2.f * __builtin_amdgcn_rcpf(e + 1.f);
}

// ---------------------------------------------------------------------------
// Pack weights into MFMA B-fragment order (bf16), and sum biases.
// Main W frags: frag = qg*40 + kc*4 + p   (qg 0..9, kc 0..9 K-chunk, p gate)
//   kc<5 -> W_ih (X part), kc>=5 -> W_hh (H part)
// Final W frags: frag = kc*8 + nt : row = nt*16+(lane&15), k<160 -> W_l, else W_r
// ---------------------------------------------------------------------------
__global__ void pack_kernel(const float* __restrict__ Wih, const float* __restrict__ Whh,
                            const float* __restrict__ bih, const float* __restrict__ bhh,
                            const float* __restrict__ Wl,  const float* __restrict__ Wr)
{
    int gid = blockIdx.x * 256 + threadIdx.x;
    if (gid < 400 * 64) {
        int frag = gid >> 6, lane = gid & 63;
        int p = frag & 3, kc = (frag >> 2) % 10, qg = frag / 40;
        int row = p * 160 + qg * 16 + (lane & 15);
        int quad = lane >> 4;
        const float* src; int k0;
        if (kc < 5) { src = Wih + row * 160; k0 = kc * 32 + quad * 8; }
        else        { src = Whh + row * 160; k0 = (kc - 5) * 32 + quad * 8; }
        ushort tmp[8];
        #pragma unroll
        for (int j = 0; j < 8; j++) tmp[j] = f2bf(src[k0 + j]);
        ((u32x4*)g_wfrag)[frag * 64 + lane] = *(const u32x4*)tmp;
    } else if (gid < 400 * 64 + 80 * 64) {
        int g2 = gid - 400 * 64;
        int frag = g2 >> 6, lane = g2 & 63;
        int nt = frag & 7, kc = frag >> 3;
        int row = nt * 16 + (lane & 15);
        int quad = lane >> 4;
        int k0 = kc * 32 + quad * 8;
        ushort tmp[8];
        #pragma unroll
        for (int j = 0; j < 8; j++) {
            int k = k0 + j;
            float v = (k < 160) ? Wl[row * 160 + k] : Wr[row * 160 + (k - 160)];
            tmp[j] = f2bf(v);
        }
        ((u32x4*)g_wlrfrag)[frag * 64 + lane] = *(const u32x4*)tmp;
    } else if (gid < 400 * 64 + 80 * 64 + 640) {
        int i = gid - (400 * 64 + 80 * 64);
        g_bsum[i] = bih[i] + bhh[i];
    }
}

// h_in = concat(x, emb[type]) as bf16 rows of 160 (320 B, 16B aligned)
__global__ void build_hin(const float* __restrict__ x, const int* __restrict__ tids,
                          const float* __restrict__ emb)
{
    int i = blockIdx.x * 256 + threadIdx.x;
    if (i >= N_NODES * F_DIM) return;
    int n = i / F_DIM, d = i - n * F_DIM;
    float v = (d < IN_CH) ? x[n * IN_CH + d] : emb[tids[n] * TYPE_DIM + (d - IN_CH)];
    g_hin[i] = f2bf(v);
}

// ---------------------------------------------------------------------------
// R4: 32-node / 5-wave (320 thr) workgroup, 2 barriers/step.
// Post-mortem R0-R3: occupancy pinned at ~0.76 blocks/CU in EVERY config
// (86/80/43 KB LDS) -> the limiter is the register-capped wave budget
// (~12-16 waves/CU at ~148 total VGPR+AGPR) QUANTIZED by the 10-wave
// workgroup to exactly 1 block/CU. Fix: 5-wave blocks so the same wave
// budget hosts 2-3 INDEPENDENT blocks whose barriers interleave (latency
// hiding across blocks, m114). Each wave owns TWO col-groups (qgA=wv,
// qgB=wv+5); per-wave regs unchanged (acc[2][2][4] = 64).
// wreg[40] array dropped (spill source: WRITE_SIZE 568MB vs 26MB output);
// weights streamed per-kc from L2 like the proven sb loop.
// LDS 21.5 KB/block (non-binding). No min-wave forcing (R2 lesson).
// ---------------------------------------------------------------------------
__launch_bounds__(NTHR)
__global__ void lstm_sage_32(const int* __restrict__ edge_src,
                             const float* __restrict__ bl,
                             float* __restrict__ out)
{
    __shared__ ushort Xb[BROWS * LS];
    __shared__ ushort Hb[BROWS * LS];

    const int tid  = threadIdx.x;
    const int lane = tid & 63;
    const int wv   = tid >> 6;           // 0..4
    const int col  = lane & 15, quad = lane >> 4;
    const int nb   = blockIdx.x * BROWS;

    const int qgA = wv, qgB = wv + 5;

    float bG[2][4];
    #pragma unroll
    for (int p = 0; p < 4; p++) {
        bG[0][p] = g_bsum[p * 160 + qgA * 16 + col];
        bG[1][p] = g_bsum[p * 160 + qgB * 16 + col];
    }

    for (int i = tid; i < BROWS * LS; i += NTHR) Hb[i] = 0;   // h(-1) = 0

    float c_st[2][2][4];                 // [m][qgi][r]
    #pragma unroll
    for (int m = 0; m < 2; m++)
        #pragma unroll
        for (int q = 0; q < 2; q++)
            #pragma unroll
            for (int r = 0; r < 4; r++) c_st[m][q][r] = 0.f;

    ushort hn[2][2][4];                  // h(t) staging regs

    const int grow  = tid / 10;          // 32 rows x 10 threads
    const int gpart = tid - grow * 10;   // 0..9 -> chunks gpart, gpart+10
    const int node_g = nb + grow;
    const int own = (node_g < N_NODES ? node_g : 0);
    const int sbase = own * DEG;

    // prologue: park X(0)
    u32x4 P0, P1;
    {
        int s = edge_src[sbase];
        const u32x4* sp = (const u32x4*)(g_hin + s * F_DIM);
        P0 = sp[gpart]; P1 = sp[gpart + 10];
    }
    int snext = edge_src[sbase + 1];

    const int aoff = col * LS + quad * 8;          // A-frag base (rows 0..15)
    const u32x4* wqA = (const u32x4*)g_wfrag + qgA * 40 * 64 + lane;
    const u32x4* wqB = (const u32x4*)g_wfrag + qgB * 40 * 64 + lane;

    #pragma unroll 1
    for (int t = 0; t < NSTEP; t++) {
        // commit h(t-1) regs and parked gather X(t) to LDS
        if (t > 0) {
            #pragma unroll
            for (int m = 0; m < 2; m++)
                #pragma unroll
                for (int r = 0; r < 4; r++) {
                    int rowoff = (m * 16 + quad * 4 + r) * LS + col;
                    Hb[rowoff + qgA * 16] = hn[m][0][r];
                    Hb[rowoff + qgB * 16] = hn[m][1][r];
                }
        }
        {
            u32x4* dp = (u32x4*)(Xb + grow * LS);
            dp[gpart] = P0; dp[gpart + 10] = P1;
        }
        __syncthreads();

        // park next gather (t=15: own h_in row for the epilogue)
        {
            const u32x4* sp = (t < NSTEP - 1)
                ? (const u32x4*)(g_hin + snext * F_DIM)
                : (const u32x4*)(g_hin + own * F_DIM);
            P0 = sp[gpart]; P1 = sp[gpart + 10];
            snext = edge_src[sbase + ((t + 2 < DEG) ? t + 2 : 0)];
        }

        f32x4 acc[2][2][4];              // [m][qgi][p]
        #pragma unroll
        for (int m = 0; m < 2; m++)
            #pragma unroll
            for (int q = 0; q < 2; q++)
                #pragma unroll
                for (int p = 0; p < 4; p++)
                    acc[m][q][p] = (f32x4){bG[q][p], bG[q][p], bG[q][p], bG[q][p]};

        #pragma unroll
        for (int kc = 0; kc < 10; kc++) {
            bf16x8 bfrA[4], bfrB[4];
            #pragma unroll
            for (int p = 0; p < 4; p++) {
                u32x4 uA = wqA[(kc * 4 + p) * 64];
                u32x4 uB = wqB[(kc * 4 + p) * 64];
                bfrA[p] = *(const bf16x8*)&uA;
                bfrB[p] = *(const bf16x8*)&uB;
            }
            const ushort* ab = ((kc < 5) ? (Xb + kc * 32) : (Hb + (kc - 5) * 32)) + aoff;
            bf16x8 afr[2];
            #pragma unroll
            for (int m = 0; m < 2; m++)
                afr[m] = *(const bf16x8*)(ab + m * (16 * LS));
            #pragma unroll
            for (int m = 0; m < 2; m++)
                #pragma unroll
                for (int p = 0; p < 4; p++) {
                    acc[m][0][p] = __builtin_amdgcn_mfma_f32_16x16x32_bf16(
                        afr[m], bfrA[p], acc[m][0][p], 0, 0, 0);
                    acc[m][1][p] = __builtin_amdgcn_mfma_f32_16x16x32_bf16(
                        afr[m], bfrB[p], acc[m][1][p], 0, 0, 0);
                }
        }

        // elementwise -> h(t) staged in regs (committed at next loop top)
        #pragma unroll
        for (int m = 0; m < 2; m++)
            #pragma unroll
            for (int q = 0; q < 2; q++)
                #pragma unroll
                for (int r = 0; r < 4; r++) {
                    float c = sigmoid_fast(acc[m][q][1][r]) * c_st[m][q][r]
                            + sigmoid_fast(acc[m][q][0][r]) * tanh_fast(acc[m][q][2][r]);
                    c_st[m][q][r] = c;
                    float h = sigmoid_fast(acc[m][q][3][r]) * tanh_fast(c);
                    hn[m][q][r] = f2bf(h);
                }
        __syncthreads();
    }

    // final commit: Hb = h(15), Xb = own h_in rows (parked at t=15)
    #pragma unroll
    for (int m = 0; m < 2; m++)
        #pragma unroll
        for (int r = 0; r < 4; r++) {
            int rowoff = (m * 16 + quad * 4 + r) * LS + col;
            Hb[rowoff + qgA * 16] = hn[m][0][r];
            Hb[rowoff + qgB * 16] = hn[m][1][r];
        }
    {
        u32x4* dp = (u32x4*)(Xb + grow * LS);
        dp[gpart] = P0; dp[gpart + 10] = P1;
    }
    __syncthreads();

    // out = relu([h_last | h_in] @ [W_l | W_r]^T + b_l)
    // waves 0..3: nt pair {2wv, 2wv+1}, both m tiles; wave 4 idle.
    if (wv < 4) {
        const int nt0 = wv * 2;
        f32x4 acc2[2][2];                // [m][j]  (nt = nt0+j)
        #pragma unroll
        for (int j = 0; j < 2; j++) {
            float b = bl[(nt0 + j) * 16 + col];
            acc2[0][j] = (f32x4){b, b, b, b};
            acc2[1][j] = (f32x4){b, b, b, b};
        }
        const u32x4* wq2 = (const u32x4*)g_wlrfrag + lane;
        #pragma unroll
        for (int kc = 0; kc < 10; kc++) {
            bf16x8 bfr[2];
            #pragma unroll
            for (int j = 0; j < 2; j++) {
                u32x4 u = wq2[(kc * 8 + nt0 + j) * 64];
                bfr[j] = *(const bf16x8*)&u;
            }
            const int bk = (kc < 5) ? kc : (kc - 5);
            const ushort* base = (kc < 5) ? Hb : Xb;   // h_last | h_in order
            #pragma unroll
            for (int m = 0; m < 2; m++) {
                const ushort* ab = base + bk * 32 + (m * 16 + col) * LS + quad * 8;
                bf16x8 afr = *(const bf16x8*)ab;
                #pragma unroll
                for (int j = 0; j < 2; j++)
                    acc2[m][j] = __builtin_amdgcn_mfma_f32_16x16x32_bf16(
                        afr, bfr[j], acc2[m][j], 0, 0, 0);
            }
        }
        #pragma unroll
        for (int m = 0; m < 2; m++)
            #pragma unroll
            for (int j = 0; j < 2; j++) {
                int ocol = (nt0 + j) * 16 + col;
                #pragma unroll
                for (int r = 0; r < 4; r++) {
                    int node = nb + m * 16 + quad * 4 + r;
                    if (node < N_NODES) {
                        float v = acc2[m][j][r];
                        out[node * OUT_CH + ocol] = v > 0.f ? v : 0.f;
                    }
                }
            }
    }
}

extern "C" void kernel_launch(void* const* d_in, const int* in_sizes, int n_in,
                              void* d_out, int out_size, void* d_ws, size_t ws_size,
                              hipStream_t stream)
{
    const float* x      = (const float*)d_in[0];
    const int*   tids   = (const int*)  d_in[1];
    const int*   esrc   = (const int*)  d_in[2];   // edge_index[0] = src (dst sorted, DEG each)
    const float* emb    = (const float*)d_in[3];
    const float* Wih    = (const float*)d_in[4];
    const float* Whh    = (const float*)d_in[5];
    const float* bih    = (const float*)d_in[6];
    const float* bhh    = (const float*)d_in[7];
    const float* Wl     = (const float*)d_in[8];
    const float* blin   = (const float*)d_in[9];
    const float* Wr     = (const float*)d_in[10];
    float* out = (float*)d_out;

    hipLaunchKernelGGL(pack_kernel, dim3(123), dim3(256), 0, stream,
                       Wih, Whh, bih, bhh, Wl, Wr);
    hipLaunchKernelGGL(build_hin, dim3((N_NODES * F_DIM + 255) / 256), dim3(256), 0, stream,
                       x, tids, emb);

    hipLaunchKernelGGL(lstm_sage_32, dim3((N_NODES + BROWS - 1) / BROWS), dim3(NTHR),
                       0, stream, esrc, blin, out);
}